// Round 10
// baseline (571.557 us; speedup 1.0000x reference)
//
#include <hip/hip_runtime.h>
#include <math.h>

constexpr int kB = 4, kN = 4096, kK = 16;
constexpr int kRows = kB * kN;          // 16384
constexpr float kEps = 1e-5f;
constexpr float kFltMax = 3.402823466e38f;
constexpr int kCap = 240;               // per-wave qualifier buffer (knn)

typedef __attribute__((ext_vector_type(8))) short short8;
typedef __attribute__((ext_vector_type(4))) float f32x4;

// bf16 round-half-up (2 ops; <=1 ulp vs RNE, inside margin)
__device__ __forceinline__ unsigned short f2bf(float x) {
  return (unsigned short)((__float_as_uint(x) + 0x8000u) >> 16);
}
__device__ __forceinline__ unsigned int pkbf(float lo, float hi) {
  return ((__float_as_uint(lo) + 0x8000u) >> 16) |
         ((__float_as_uint(hi) + 0x8000u) & 0xffff0000u);
}
__device__ __forceinline__ short8 pack8f(float4 a, float4 b) {
  union { unsigned int u[4]; short8 s; } pk;
  pk.u[0] = pkbf(a.x, a.y);
  pk.u[1] = pkbf(a.z, a.w);
  pk.u[2] = pkbf(b.x, b.y);
  pk.u[3] = pkbf(b.z, b.w);
  return pk.s;
}

// Full 64-lane bitonic sort, ascending by (v, i) lexicographic.
__device__ __forceinline__ void bitonic64(float& sv, int& si, int lane) {
  #pragma unroll
  for (int k = 2; k <= 64; k <<= 1) {
    #pragma unroll
    for (int j = k >> 1; j > 0; j >>= 1) {
      float ov = __shfl_xor(sv, j);
      int   oi = __shfl_xor(si, j);
      bool up = ((lane & k) == 0);
      bool lower = ((lane & j) == 0);
      bool osm = (ov < sv) || (ov == sv && oi < si);
      bool take = (lower == up) ? osm : !osm;
      if (take) { sv = ov; si = oi; }
    }
  }
}

// ---------------- prep: fc1 MFMA + weight pre-pack + p4 pack + fused stats1 ----------------
__global__ __launch_bounds__(256) void prep_kernel(
    const float* __restrict__ x, const float* __restrict__ w,
    const float* __restrict__ bias,
    const float* __restrict__ aw1, const float* __restrict__ aw2,
    const float* __restrict__ pw2, const float* __restrict__ qw,
    const float* __restrict__ f2w, const float* __restrict__ p,
    const float* __restrict__ g1, const float* __restrict__ b1,
    unsigned short* __restrict__ wpak, float* __restrict__ out,
    float4* __restrict__ p4,
    float* __restrict__ sacc, int* __restrict__ cnts,
    float* __restrict__ A1, float* __restrict__ B1) {
  __shared__ unsigned short wf[8 * 512];   // fc1_w B-frags, 8 KB
  const int t = threadIdx.x;
  const int blk = blockIdx.x;              // 256 blocks
  {
    int id = blk * 256 + t;
    if (id < 16384) {
      int j = id & 7, lane = (id >> 3) & 63, rest = id >> 9;
      int mt = rest >> 1, hh = rest & 1;
      wpak[id] = f2bf(aw1[(32 * hh + 8 * (lane >> 4) + j) * 256 + mt * 16 + (lane & 15)]);
    } else if (id < 32768) {
      int i = id - 16384;
      int j = i & 7, lane = (i >> 3) & 63, rest = i >> 9;
      int ct = rest >> 3, f = rest & 7;
      wpak[id] = f2bf(aw2[(32 * f + 8 * (lane >> 4) + j) * 64 + ct * 16 + (lane & 15)]);
    } else if (id < 34816) {
      int i = id - 32768;
      int c = i >> 5, hh = i & 31;
      wpak[id] = f2bf(pw2[hh * 64 + c]);
    } else if (id < 47104) {
      int i = id - 34816;
      int j = i & 7, lane = (i >> 3) & 63, rest = i >> 9;
      int ct = rest >> 1, hh = rest & 1;
      wpak[id] = f2bf(qw[(32 * hh + 8 * (lane >> 4) + j) * 192 + ct * 16 + (lane & 15)]);
    } else if (id < 51200) {
      int i = id - 47104;
      int j = i & 7, lane = (i >> 3) & 63, rest = i >> 9;
      int ct = rest >> 1, hh = rest & 1;
      wpak[id] = f2bf(f2w[(32 * hh + 8 * (lane >> 4) + j) * 64 + ct * 16 + (lane & 15)]);
    }
  }
  // p4 pack: 64 points per block
  if (t < 64) {
    int idx = blk * 64 + t;
    float px = p[3 * idx], py = p[3 * idx + 1], pz = p[3 * idx + 2];
    p4[idx] = make_float4(px, py, pz, px * px + py * py + pz * pz);
  }
  for (int i = t; i < 4096; i += 256) {
    int j = i & 7, lane = (i >> 3) & 63, rest = i >> 9;
    int ct = rest >> 1, hh = rest & 1;
    wf[i] = f2bf(w[(32 * hh + 8 * (lane >> 4) + j) * 64 + ct * 16 + (lane & 15)]);
  }
  __syncthreads();
  const int lane = t & 63, wv = t >> 6;
  const int l = lane & 15, q = lane >> 4;
  const int r0 = blk * 64;
  const int row = r0 + wv * 16 + l;
  const f32x4 zero = {0.f, 0.f, 0.f, 0.f};
  float4 xa0 = *reinterpret_cast<const float4*>(&x[row * 64 + q * 8]);
  float4 xa1 = *reinterpret_cast<const float4*>(&x[row * 64 + q * 8 + 4]);
  float4 xb0 = *reinterpret_cast<const float4*>(&x[row * 64 + 32 + q * 8]);
  float4 xb1 = *reinterpret_cast<const float4*>(&x[row * 64 + 32 + q * 8 + 4]);
  short8 a0 = pack8f(xa0, xa1), a1 = pack8f(xb0, xb1);
  float s[4], s2[4];
  #pragma unroll
  for (int ct = 0; ct < 4; ++ct) {
    short8 b0 = *reinterpret_cast<const short8*>(&wf[(ct * 2 + 0) * 512 + lane * 8]);
    short8 b1v = *reinterpret_cast<const short8*>(&wf[(ct * 2 + 1) * 512 + lane * 8]);
    f32x4 acc = __builtin_amdgcn_mfma_f32_16x16x32_bf16(a0, b0, zero, 0, 0, 0);
    acc = __builtin_amdgcn_mfma_f32_16x16x32_bf16(a1, b1v, acc, 0, 0, 0);
    const float bc = bias[ct * 16 + l];
    float ls = 0.f, ls2 = 0.f;
    #pragma unroll
    for (int i = 0; i < 4; ++i) {
      float v = acc[i] + bc;
      out[(r0 + wv * 16 + q * 4 + i) * 64 + ct * 16 + l] = v;
      ls += v; ls2 += v * v;
    }
    s[ct] = ls; s2[ct] = ls2;
  }
  // fused stats1: reduce over q (lane bits 4,5), atomicAdd into banked accum
  #pragma unroll
  for (int ct = 0; ct < 4; ++ct) {
    s[ct]  += __shfl_xor(s[ct], 16);  s[ct]  += __shfl_xor(s[ct], 32);
    s2[ct] += __shfl_xor(s2[ct], 16); s2[ct] += __shfl_xor(s2[ct], 32);
  }
  if (q == 0) {
    const int bank = blk & 15;
    #pragma unroll
    for (int ct = 0; ct < 4; ++ct) {
      atomicAdd(&sacc[bank * 128 + ct * 16 + l], s[ct]);
      atomicAdd(&sacc[bank * 128 + 64 + ct * 16 + l], s2[ct]);
    }
  }
  __threadfence();
  int old = 0;
  if (lane == 0) old = atomicAdd(&cnts[0], 1);
  old = __shfl(old, 0);
  if (old == 1023) {            // last of 1024 waves: finalize A1/B1
    __threadfence();
    float ss = 0.f, ss2 = 0.f;
    #pragma unroll
    for (int bk = 0; bk < 16; ++bk) {
      ss  += sacc[bk * 128 + lane];
      ss2 += sacc[bk * 128 + 64 + lane];
    }
    double mean = (double)ss / (double)kRows;
    double var = (double)ss2 / (double)kRows - mean * mean;
    float rs = (float)(1.0 / sqrt(var + (double)kEps));
    float Af = g1[lane] * rs;
    A1[lane] = Af;
    B1[lane] = b1[lane] - (float)mean * Af;
  }
}

// ---------------- fused qkv (blocks 0..255) + knn (blocks 256..4351) ----------------
__global__ __launch_bounds__(256) void qkv_knn_kernel(
    const float* __restrict__ hpre, const float* __restrict__ A1,
    const float* __restrict__ B1, const unsigned short* __restrict__ wqf,
    float* __restrict__ hout, unsigned short* __restrict__ qkvout,
    const float4* __restrict__ p4, int* __restrict__ idxf) {
  __shared__ float bufv[4][kCap];
  __shared__ int   bufi[4][kCap];
  __shared__ int   cnt[4];
  const int t = threadIdx.x;
  const int lane = t & 63, w = t >> 6;

  if (blockIdx.x < 256) {
    // ---- qkv branch: MFMA with fused bn1+relu; h fp32 + qkv bf16 ----
    const int l = lane & 15, q = lane >> 4;
    const int r0 = blockIdx.x * 64;
    const int row = r0 + w * 16 + l;
    const f32x4 zero = {0.f, 0.f, 0.f, 0.f};
    short8 af[2];
    #pragma unroll
    for (int hh = 0; hh < 2; ++hh) {
      const int c0 = 32 * hh + q * 8;
      float4 v0 = *reinterpret_cast<const float4*>(&hpre[row * 64 + c0]);
      float4 v1 = *reinterpret_cast<const float4*>(&hpre[row * 64 + c0 + 4]);
      float4 Aa = *reinterpret_cast<const float4*>(&A1[c0]);
      float4 Ab = *reinterpret_cast<const float4*>(&A1[c0 + 4]);
      float4 Ba = *reinterpret_cast<const float4*>(&B1[c0]);
      float4 Bb = *reinterpret_cast<const float4*>(&B1[c0 + 4]);
      v0.x = fmaxf(Aa.x * v0.x + Ba.x, 0.f); v0.y = fmaxf(Aa.y * v0.y + Ba.y, 0.f);
      v0.z = fmaxf(Aa.z * v0.z + Ba.z, 0.f); v0.w = fmaxf(Aa.w * v0.w + Ba.w, 0.f);
      v1.x = fmaxf(Ab.x * v1.x + Bb.x, 0.f); v1.y = fmaxf(Ab.y * v1.y + Bb.y, 0.f);
      v1.z = fmaxf(Ab.z * v1.z + Bb.z, 0.f); v1.w = fmaxf(Ab.w * v1.w + Bb.w, 0.f);
      *reinterpret_cast<float4*>(&hout[row * 64 + c0]) = v0;
      *reinterpret_cast<float4*>(&hout[row * 64 + c0 + 4]) = v1;
      af[hh] = pack8f(v0, v1);
    }
    #pragma unroll
    for (int ct = 0; ct < 12; ++ct) {
      short8 b0 = *reinterpret_cast<const short8*>(&wqf[((ct * 2 + 0) * 64 + lane) * 8]);
      short8 b1 = *reinterpret_cast<const short8*>(&wqf[((ct * 2 + 1) * 64 + lane) * 8]);
      f32x4 acc = __builtin_amdgcn_mfma_f32_16x16x32_bf16(af[0], b0, zero, 0, 0, 0);
      acc = __builtin_amdgcn_mfma_f32_16x16x32_bf16(af[1], b1, acc, 0, 0, 0);
      #pragma unroll
      for (int i = 0; i < 4; ++i)
        qkvout[(r0 + w * 16 + q * 4 + i) * 192 + ct * 16 + l] = f2bf(acc[i]);
    }
    return;
  }

  // ---- knn branch: barrier-free filtered top-16 over packed p4 ----
  const int blk = blockIdx.x - 256;
  const int b = blk >> 10;
  const int q = blk * 4 + w;
  const float4 qp = p4[q];
  const float m2x = -2.0f * qp.x, m2y = -2.0f * qp.y, m2z = -2.0f * qp.z;
  const float sqw = qp.w;
  if (lane == 0) cnt[w] = 0;
  const int base = b * kN;

  float d2r[16];
  float lmin = kFltMax;
  #pragma unroll
  for (int i = 0; i < 16; ++i) {
    float4 c = p4[base + i * 64 + lane];
    float d2 = fmaf(m2x, c.x, fmaf(m2y, c.y, fmaf(m2z, c.z, sqw + c.w)));
    d2r[i] = d2;
    lmin = fminf(lmin, d2);
  }
  { int dummy = lane; bitonic64(lmin, dummy, lane); }
  const float thrA = __shfl(lmin, 15) + 1e-3f;  // cross-site FMA-wobble margin

  #pragma unroll
  for (int i = 0; i < 16; ++i) {
    if (d2r[i] <= thrA) {
      int pos = atomicAdd(&cnt[w], 1);
      if (pos < kCap) { bufv[w][pos] = d2r[i]; bufi[w][pos] = i * 64 + lane; }
    }
  }
  for (int i = 16; i < 64; ++i) {
    float4 c = p4[base + i * 64 + lane];
    float d2 = fmaf(m2x, c.x, fmaf(m2y, c.y, fmaf(m2z, c.z, sqw + c.w)));
    if (d2 <= thrA) {
      int pos = atomicAdd(&cnt[w], 1);
      if (pos < kCap) { bufv[w][pos] = d2; bufi[w][pos] = i * 64 + lane; }
    }
  }

  const int n = cnt[w];   // same-wave LDS ops are ordered
  float sv = kFltMax;
  int   si = 0x7fffffff;
  if (n <= kCap) {
    for (int g0 = 0; g0 < n; g0 += 48) {
      float mv; int mi;
      if (lane < 16) { mv = sv; mi = si; }
      else {
        int pos = g0 + (lane - 16);
        if (pos < n) { mv = bufv[w][pos]; mi = bufi[w][pos]; }
        else { mv = kFltMax; mi = 0x7fffffff; }
      }
      bitonic64(mv, mi, lane);
      sv = mv; si = mi;
    }
  } else {
    for (int g0 = 0; g0 < kN; g0 += 48) {   // degenerate-data slow path
      float mv; int mi;
      if (lane < 16) { mv = sv; mi = si; }
      else {
        int j = g0 + (lane - 16);
        if (j < kN) {
          float4 c = p4[base + j];
          mv = fmaf(m2x, c.x, fmaf(m2y, c.y, fmaf(m2z, c.z, sqw + c.w)));
          mi = j;
        } else { mv = kFltMax; mi = 0x7fffffff; }
      }
      bitonic64(mv, mi, lane);
      sv = mv; si = mi;
    }
  }
  if (lane < 16) {
    int out = si;
    if ((unsigned)out >= (unsigned)kN) out = 0;  // safety net: wrong beats fault
    idxf[q * 16 + lane] = out;
  }
}

// ---------------- fused MFMA attention v5: v4 body + fused stats2 ----------------
__global__ __launch_bounds__(256) void attn_mfma5_kernel(
    const float* __restrict__ p, const unsigned short* __restrict__ qkv,
    const int* __restrict__ idxf,
    const float* __restrict__ pos_w1, const float* __restrict__ pos_b1,
    const float* __restrict__ pos_b2,
    const float* __restrict__ attn_b1, const float* __restrict__ attn_b2,
    const unsigned short* __restrict__ w1f,
    const unsigned short* __restrict__ w2f,
    const unsigned short* __restrict__ pw2t,
    const float* __restrict__ g2, const float* __restrict__ b2g,
    float* __restrict__ agg,
    float* __restrict__ sacc, int* __restrict__ bcnt, int* __restrict__ cnts,
    float* __restrict__ A2, float* __restrict__ B2) {
  __shared__ unsigned short Ulds[64 * 72];   // [row][c] bf16, stride 72
  __shared__ float VVlds[64 * 68];           // [row][c] fp32, stride 68

  const int t = threadIdx.x;
  const int lane = t & 63, w = t >> 6;
  const int l = lane & 15, q = lane >> 4;
  const int work = ((blockIdx.x & 7) << 9) | (blockIdx.x >> 3);  // XCD swizzle
  const int b = work >> 10;
  const int n0 = (work & 1023) * 4;
  const int pt_row = b * kN + n0 + w;
  const f32x4 zero = {0.f, 0.f, 0.f, 0.f};

  int idxv = 0;
  if (lane < 16) idxv = idxf[(work * 4 + w) * 16 + lane];

  // phase 1a: gather k/v (bf16); U = bf16(q - k); VV[row][c] = v
  {
    const int r = lane >> 2, seg = lane & 3;
    const unsigned short* jrow = qkv + (b * kN + __shfl(idxv, r)) * 192;
    const int c0 = seg * 16;
    uint4 k0 = *reinterpret_cast<const uint4*>(jrow + 64 + c0);
    uint4 k1 = *reinterpret_cast<const uint4*>(jrow + 64 + c0 + 8);
    uint4 v0 = *reinterpret_cast<const uint4*>(jrow + 128 + c0);
    uint4 v1 = *reinterpret_cast<const uint4*>(jrow + 128 + c0 + 8);
    uint4 q0 = *reinterpret_cast<const uint4*>(qkv + pt_row * 192 + c0);
    uint4 q1 = *reinterpret_cast<const uint4*>(qkv + pt_row * 192 + c0 + 8);
    auto diff2 = [](unsigned int qu, unsigned int ku) -> unsigned int {
      float lo = __uint_as_float(qu << 16) - __uint_as_float(ku << 16);
      float hi = __uint_as_float(qu & 0xffff0000u) - __uint_as_float(ku & 0xffff0000u);
      return pkbf(lo, hi);
    };
    uint4 u0, u1;
    u0.x = diff2(q0.x, k0.x); u0.y = diff2(q0.y, k0.y);
    u0.z = diff2(q0.z, k0.z); u0.w = diff2(q0.w, k0.w);
    u1.x = diff2(q1.x, k1.x); u1.y = diff2(q1.y, k1.y);
    u1.z = diff2(q1.z, k1.z); u1.w = diff2(q1.w, k1.w);
    *reinterpret_cast<uint4*>(&Ulds[(w * 16 + r) * 72 + c0]) = u0;
    *reinterpret_cast<uint4*>(&Ulds[(w * 16 + r) * 72 + c0 + 8]) = u1;
    const unsigned int vs[8] = {v0.x, v0.y, v0.z, v0.w, v1.x, v1.y, v1.z, v1.w};
    #pragma unroll
    for (int i = 0; i < 4; ++i) {
      float4 vv;
      vv.x = __uint_as_float(vs[2 * i] << 16);
      vv.y = __uint_as_float(vs[2 * i] & 0xffff0000u);
      vv.z = __uint_as_float(vs[2 * i + 1] << 16);
      vv.w = __uint_as_float(vs[2 * i + 1] & 0xffff0000u);
      *reinterpret_cast<float4*>(&VVlds[(w * 16 + r) * 68 + c0 + 4 * i]) = vv;
    }
  }
  // phase 1b: pe hidden (3->32) — registers only
  short8 pbf;
  {
    const float3 pn = *reinterpret_cast<const float3*>(p + pt_row * 3);
    const int nj = __shfl(idxv, l);
    const float3 pj = *reinterpret_cast<const float3*>(p + (b * kN + nj) * 3);
    float rx = pn.x - pj.x, ry = pn.y - pj.y, rz = pn.z - pj.z;
    float hv[8];
    #pragma unroll
    for (int j = 0; j < 8; ++j) {
      int hh = q * 8 + j;
      hv[j] = fmaxf(pos_b1[hh] + rx * pos_w1[hh] + ry * pos_w1[32 + hh] +
                    rz * pos_w1[64 + hh], 0.0f);
    }
    union { unsigned int u[4]; short8 s; } pk;
    #pragma unroll
    for (int ii = 0; ii < 4; ++ii) pk.u[ii] = pkbf(hv[2 * ii], hv[2 * ii + 1]);
    pbf = pk.s;
  }

  // phase 2: pe = pehid @ pos_w2 (transposed MFMA, D[c][row]); RMW U and VV
  {
    const int urow = (w * 16 + l) * 72;
    const int vrow = (w * 16 + l) * 68;
    #pragma unroll
    for (int mt = 0; mt < 4; ++mt) {
      short8 paf = *reinterpret_cast<const short8*>(&pw2t[(mt * 16 + l) * 32 + q * 8]);
      f32x4 pe = __builtin_amdgcn_mfma_f32_16x16x32_bf16(paf, pbf, zero, 0, 0, 0);
      const int c0 = mt * 16 + q * 4;
      float4 b2v = *reinterpret_cast<const float4*>(&pos_b2[c0]);
      float pe0 = pe[0] + b2v.x, pe1 = pe[1] + b2v.y;
      float pe2 = pe[2] + b2v.z, pe3 = pe[3] + b2v.w;
      uint2 u2 = *reinterpret_cast<uint2*>(&Ulds[urow + c0]);
      uint2 o;
      o.x = pkbf(__uint_as_float(u2.x << 16) + pe0,
                 __uint_as_float(u2.x & 0xffff0000u) + pe1);
      o.y = pkbf(__uint_as_float(u2.y << 16) + pe2,
                 __uint_as_float(u2.y & 0xffff0000u) + pe3);
      *reinterpret_cast<uint2*>(&Ulds[urow + c0]) = o;
      float4 vv = *reinterpret_cast<float4*>(&VVlds[vrow + c0]);
      vv.x += pe0; vv.y += pe1; vv.z += pe2; vv.w += pe3;
      *reinterpret_cast<float4*>(&VVlds[vrow + c0]) = vv;
    }
  }

  // phase 3: GEMM1 transposed; H packed to bf16 dwords immediately
  unsigned int plo[16], phi[16];
  {
    const int urow = (w * 16 + l) * 72;
    short8 ub0 = *reinterpret_cast<const short8*>(&Ulds[urow + q * 8]);
    short8 ub1 = *reinterpret_cast<const short8*>(&Ulds[urow + 32 + q * 8]);
    #pragma unroll
    for (int mt = 0; mt < 16; ++mt) {
      short8 a0 = *reinterpret_cast<const short8*>(&w1f[(mt * 2 + 0) * 512 + lane * 8]);
      short8 a1 = *reinterpret_cast<const short8*>(&w1f[(mt * 2 + 1) * 512 + lane * 8]);
      f32x4 acc = __builtin_amdgcn_mfma_f32_16x16x32_bf16(a0, ub0, zero, 0, 0, 0);
      acc = __builtin_amdgcn_mfma_f32_16x16x32_bf16(a1, ub1, acc, 0, 0, 0);
      float4 bb = *reinterpret_cast<const float4*>(&attn_b1[mt * 16 + q * 4]);
      plo[mt] = pkbf(fmaxf(acc[0] + bb.x, 0.f), fmaxf(acc[1] + bb.y, 0.f));
      phi[mt] = pkbf(fmaxf(acc[2] + bb.z, 0.f), fmaxf(acc[3] + bb.w, 0.f));
    }
  }

  // phase 4: GEMM2 via cheap repack; softmax; weighted sum of VV; fused stats2
  float outv[4];
  {
    f32x4 acc2[4];
    #pragma unroll
    for (int ct = 0; ct < 4; ++ct) acc2[ct] = zero;
    const int sbase = l + 32 * (q & 1);
    const bool hi_mt = (q >= 2);
    #pragma unroll
    for (int f = 0; f < 8; ++f) {
      union { unsigned int u[4]; short8 s; } pk;
      #pragma unroll
      for (int d = 0; d < 4; ++d) {
        const int src = sbase + ((d >> 1) << 4);
        const unsigned int w0 = (d & 1) ? phi[2 * f] : plo[2 * f];
        const unsigned int w1v = (d & 1) ? phi[2 * f + 1] : plo[2 * f + 1];
        unsigned int va = (unsigned int)__shfl((int)w0, src);
        unsigned int vb = (unsigned int)__shfl((int)w1v, src);
        pk.u[d] = hi_mt ? vb : va;
      }
      short8 afr = pk.s;
      #pragma unroll
      for (int ct = 0; ct < 4; ++ct) {
        short8 bfr = *reinterpret_cast<const short8*>(&w2f[((ct * 8 + f) * 64 + lane) * 8]);
        acc2[ct] = __builtin_amdgcn_mfma_f32_16x16x32_bf16(afr, bfr, acc2[ct], 0, 0, 0);
      }
    }
    #pragma unroll
    for (int ct = 0; ct < 4; ++ct) {
      const int ch = ct * 16 + l;
      const float bv = attn_b2[ch];
      float s0v = acc2[ct][0] + bv, s1v = acc2[ct][1] + bv;
      float s2v = acc2[ct][2] + bv, s3v = acc2[ct][3] + bv;
      float mx = fmaxf(fmaxf(s0v, s1v), fmaxf(s2v, s3v));
      mx = fmaxf(mx, __shfl_xor(mx, 16, 64));
      mx = fmaxf(mx, __shfl_xor(mx, 32, 64));
      float e0 = __expf(s0v - mx), e1 = __expf(s1v - mx);
      float e2 = __expf(s2v - mx), e3 = __expf(s3v - mx);
      float se = e0 + e1 + e2 + e3;
      se += __shfl_xor(se, 16, 64);
      se += __shfl_xor(se, 32, 64);
      const int vbase = (w * 16 + q * 4) * 68 + ch;
      float a = e0 * VVlds[vbase] + e1 * VVlds[vbase + 68] +
                e2 * VVlds[vbase + 136] + e3 * VVlds[vbase + 204];
      a += __shfl_xor(a, 16, 64);
      a += __shfl_xor(a, 32, 64);
      float r = a / se;
      outv[ct] = r;
      if (q == 0) agg[(work * 4 + w) * 64 + ch] = r;
    }
  }
  // fused stats2: per-wave banked atomics + block counter + global counter
  if (q == 0) {
    const int bank = work & 15;
    #pragma unroll
    for (int ct = 0; ct < 4; ++ct) {
      const int ch = ct * 16 + l;
      float r = outv[ct];
      atomicAdd(&sacc[bank * 128 + ch], r);
      atomicAdd(&sacc[bank * 128 + 64 + ch], r * r);
    }
  }
  __threadfence();
  int oldw = 0;
  if (lane == 0) oldw = atomicAdd(&bcnt[work], 1);
  oldw = __shfl(oldw, 0);
  if (oldw == 3) {              // last wave of this block
    int oldb = 0;
    if (lane == 0) oldb = atomicAdd(&cnts[1], 1);
    oldb = __shfl(oldb, 0);
    if (oldb == 4095) {         // last block: finalize A2/B2
      __threadfence();
      float ss = 0.f, ss2 = 0.f;
      #pragma unroll
      for (int bk = 0; bk < 16; ++bk) {
        ss  += sacc[bk * 128 + lane];
        ss2 += sacc[bk * 128 + 64 + lane];
      }
      double mean = (double)ss / (double)kRows;
      double var = (double)ss2 / (double)kRows - mean * mean;
      float rs = (float)(1.0 / sqrt(var + (double)kEps));
      float Af = g2[lane] * rs;
      A2[lane] = Af;
      B2[lane] = b2g[lane] - (float)mean * Af;
    }
  }
}

// ---------------- fc2 (MFMA) + bn2/relu/residual prologue + fused stats3 ----------------
__global__ __launch_bounds__(256) void fc2_mfma_kernel(
    const float* __restrict__ aggp, const float* __restrict__ hres,
    const float* __restrict__ A2, const float* __restrict__ B2,
    const unsigned short* __restrict__ fc2f, const float* __restrict__ bias,
    const float* __restrict__ g3, const float* __restrict__ b3,
    float* __restrict__ z,
    float* __restrict__ sacc, int* __restrict__ cnts,
    float* __restrict__ A3, float* __restrict__ B3) {
  const int t = threadIdx.x, lane = t & 63, wv = t >> 6;
  const int l = lane & 15, q = lane >> 4;
  const int r0 = blockIdx.x * 64;
  const int row = r0 + wv * 16 + l;
  const f32x4 zero = {0.f, 0.f, 0.f, 0.f};
  short8 af[2];
  #pragma unroll
  for (int hh = 0; hh < 2; ++hh) {
    const int c0 = 32 * hh + q * 8;
    float4 v0 = *reinterpret_cast<const float4*>(&aggp[row * 64 + c0]);
    float4 v1 = *reinterpret_cast<const float4*>(&aggp[row * 64 + c0 + 4]);
    float4 r0v = *reinterpret_cast<const float4*>(&hres[row * 64 + c0]);
    float4 r1v = *reinterpret_cast<const float4*>(&hres[row * 64 + c0 + 4]);
    float4 Aa = *reinterpret_cast<const float4*>(&A2[c0]);
    float4 Ab = *reinterpret_cast<const float4*>(&A2[c0 + 4]);
    float4 Ba = *reinterpret_cast<const float4*>(&B2[c0]);
    float4 Bb = *reinterpret_cast<const float4*>(&B2[c0 + 4]);
    v0.x = fmaxf(Aa.x * v0.x + Ba.x, 0.f) + r0v.x;
    v0.y = fmaxf(Aa.y * v0.y + Ba.y, 0.f) + r0v.y;
    v0.z = fmaxf(Aa.z * v0.z + Ba.z, 0.f) + r0v.z;
    v0.w = fmaxf(Aa.w * v0.w + Ba.w, 0.f) + r0v.w;
    v1.x = fmaxf(Ab.x * v1.x + Bb.x, 0.f) + r1v.x;
    v1.y = fmaxf(Ab.y * v1.y + Bb.y, 0.f) + r1v.y;
    v1.z = fmaxf(Ab.z * v1.z + Bb.z, 0.f) + r1v.z;
    v1.w = fmaxf(Ab.w * v1.w + Bb.w, 0.f) + r1v.w;
    af[hh] = pack8f(v0, v1);
  }
  float s[4], s2[4];
  #pragma unroll
  for (int ct = 0; ct < 4; ++ct) {
    short8 b0 = *reinterpret_cast<const short8*>(&fc2f[((ct * 2 + 0) * 64 + lane) * 8]);
    short8 b1 = *reinterpret_cast<const short8*>(&fc2f[((ct * 2 + 1) * 64 + lane) * 8]);
    f32x4 acc = __builtin_amdgcn_mfma_f32_16x16x32_bf16(af[0], b0, zero, 0, 0, 0);
    acc = __builtin_amdgcn_mfma_f32_16x16x32_bf16(af[1], b1, acc, 0, 0, 0);
    const float bc = bias[ct * 16 + l];
    float ls = 0.f, ls2 = 0.f;
    #pragma unroll
    for (int i = 0; i < 4; ++i) {
      float v = acc[i] + bc;
      z[(r0 + wv * 16 + q * 4 + i) * 64 + ct * 16 + l] = v;
      ls += v; ls2 += v * v;
    }
    s[ct] = ls; s2[ct] = ls2;
  }
  #pragma unroll
  for (int ct = 0; ct < 4; ++ct) {
    s[ct]  += __shfl_xor(s[ct], 16);  s[ct]  += __shfl_xor(s[ct], 32);
    s2[ct] += __shfl_xor(s2[ct], 16); s2[ct] += __shfl_xor(s2[ct], 32);
  }
  if (q == 0) {
    const int bank = blockIdx.x & 15;
    #pragma unroll
    for (int ct = 0; ct < 4; ++ct) {
      atomicAdd(&sacc[bank * 128 + ct * 16 + l], s[ct]);
      atomicAdd(&sacc[bank * 128 + 64 + ct * 16 + l], s2[ct]);
    }
  }
  __threadfence();
  int old = 0;
  if (lane == 0) old = atomicAdd(&cnts[2], 1);
  old = __shfl(old, 0);
  if (old == 1023) {
    __threadfence();
    float ss = 0.f, ss2 = 0.f;
    #pragma unroll
    for (int bk = 0; bk < 16; ++bk) {
      ss  += sacc[bk * 128 + lane];
      ss2 += sacc[bk * 128 + 64 + lane];
    }
    double mean = (double)ss / (double)kRows;
    double var = (double)ss2 / (double)kRows - mean * mean;
    float rs = (float)(1.0 / sqrt(var + (double)kEps));
    float Af = g3[lane] * rs;
    A3[lane] = Af;
    B3[lane] = b3[lane] - (float)mean * Af;
  }
}

// ---------------- final bn3+relu, fused p-copy ----------------
__global__ void final_kernel(const float* __restrict__ z, const float* __restrict__ A3,
                             const float* __restrict__ B3, const float* __restrict__ p,
                             float* __restrict__ y) {
  const int blk = blockIdx.x, t = threadIdx.x;
  if (blk < 4096) {
    int i = blk * 256 + t;
    int c = i & 63;
    y[i] = fmaxf(A3[c] * z[i] + B3[c], 0.0f);
  } else {
    int i = (blk - 4096) * 256 + t;
    y[1048576 + i] = p[i];
  }
}

extern "C" void kernel_launch(void* const* d_in, const int* in_sizes, int n_in,
                              void* d_out, int out_size, void* d_ws, size_t ws_size,
                              hipStream_t stream) {
  const float* x       = (const float*)d_in[0];
  const float* p       = (const float*)d_in[1];
  const float* fc1_w   = (const float*)d_in[2];
  const float* fc1_b   = (const float*)d_in[3];
  const float* bn1_g   = (const float*)d_in[4];
  const float* bn1_b   = (const float*)d_in[5];
  const float* qkv_w   = (const float*)d_in[6];
  const float* pos_w1  = (const float*)d_in[7];
  const float* pos_b1  = (const float*)d_in[8];
  const float* pos_w2  = (const float*)d_in[9];
  const float* pos_b2  = (const float*)d_in[10];
  const float* attn_w1 = (const float*)d_in[11];
  const float* attn_b1 = (const float*)d_in[12];
  const float* attn_w2 = (const float*)d_in[13];
  const float* attn_b2 = (const float*)d_in[14];
  const float* bn2_g   = (const float*)d_in[15];
  const float* bn2_b   = (const float*)d_in[16];
  const float* fc2_w   = (const float*)d_in[17];
  const float* fc2_b   = (const float*)d_in[18];
  const float* bn3_g   = (const float*)d_in[19];
  const float* bn3_b   = (const float*)d_in[20];

  float* ws   = (float*)d_ws;
  float* h    = ws;                     // residual, fp32
  unsigned short* qkvb = (unsigned short*)(ws + 1048576);  // bf16 [16384][192]
  float* hpre = ws + 4194304;
  float* aggv = ws + 5242880;
  float* z    = ws + 6291456;
  float4* p4  = (float4*)(ws + 6291456);   // aliases z: consumed (knn) before fc2 writes z
  float* st   = ws + 7340032;              // A1,B1,A2,B2,A3,B3 (384 floats)
  int*   cnts = (int*)(ws + 7340416);      // 16 ints
  float* sacc1 = ws + 7340432;             // 16 banks x 128
  float* sacc2 = ws + 7342480;
  float* sacc3 = ws + 7344528;
  int*   bcnt  = (int*)(ws + 7346576);     // 4096 ints (attn per-block wave counters)
  int*   idxf  = (int*)(ws + 7356800);
  unsigned short* wpak = (unsigned short*)(ws + 7618944);
  unsigned short* w1f  = wpak;
  unsigned short* w2f  = wpak + 16384;
  unsigned short* pw2t = wpak + 32768;
  unsigned short* wqf  = wpak + 34816;
  unsigned short* fc2f = wpak + 47104;

  float* A1 = st,       *B1 = st + 64;
  float* A2 = st + 128, *B2 = st + 192;
  float* A3 = st + 256, *B3 = st + 320;
  float* y = (float*)d_out;

  // zero counters + banked accumulators + block counters (one contiguous span)
  hipMemsetAsync((char*)d_ws + 7340416ull * 4ull, 0, (16 + 3 * 2048 + 4096) * 4, stream);

  prep_kernel<<<256, 256, 0, stream>>>(x, fc1_w, fc1_b, attn_w1, attn_w2, pos_w2,
                                       qkv_w, fc2_w, p, bn1_g, bn1_b,
                                       wpak, hpre, p4, sacc1, cnts, A1, B1);
  qkv_knn_kernel<<<4352, 256, 0, stream>>>(hpre, A1, B1, wqf, h, qkvb, p4, idxf);
  attn_mfma5_kernel<<<4096, 256, 0, stream>>>(p, qkvb, idxf, pos_w1, pos_b1, pos_b2,
                                              attn_b1, attn_b2, w1f, w2f, pw2t,
                                              bn2_g, bn2_b, aggv,
                                              sacc2, bcnt, cnts, A2, B2);
  fc2_mfma_kernel<<<256, 256, 0, stream>>>(aggv, h, A2, B2, fc2f, fc2_b,
                                           bn3_g, bn3_b, z, sacc3, cnts, A3, B3);
  final_kernel<<<4288, 256, 0, stream>>>(z, A3, B3, p, y);
}

// Round 12
// 303.951 us; speedup vs baseline: 1.8804x; 1.8804x over previous
//
#include <hip/hip_runtime.h>
#include <math.h>

constexpr int kB = 4, kN = 4096, kK = 16;
constexpr int kRows = kB * kN;          // 16384
constexpr float kEps = 1e-5f;
constexpr float kFltMax = 3.402823466e38f;
constexpr int kCap = 240;               // per-wave qualifier buffer (knn)

typedef __attribute__((ext_vector_type(8))) short short8;
typedef __attribute__((ext_vector_type(4))) float f32x4;

// bf16 round-half-up (2 ops; <=1 ulp vs RNE, inside margin)
__device__ __forceinline__ unsigned short f2bf(float x) {
  return (unsigned short)((__float_as_uint(x) + 0x8000u) >> 16);
}
__device__ __forceinline__ unsigned int pkbf(float lo, float hi) {
  return ((__float_as_uint(lo) + 0x8000u) >> 16) |
         ((__float_as_uint(hi) + 0x8000u) & 0xffff0000u);
}
__device__ __forceinline__ short8 pack8f(float4 a, float4 b) {
  union { unsigned int u[4]; short8 s; } pk;
  pk.u[0] = pkbf(a.x, a.y);
  pk.u[1] = pkbf(a.z, a.w);
  pk.u[2] = pkbf(b.x, b.y);
  pk.u[3] = pkbf(b.z, b.w);
  return pk.s;
}

// Full 64-lane bitonic sort, ascending by (v, i) lexicographic.
__device__ __forceinline__ void bitonic64(float& sv, int& si, int lane) {
  #pragma unroll
  for (int k = 2; k <= 64; k <<= 1) {
    #pragma unroll
    for (int j = k >> 1; j > 0; j >>= 1) {
      float ov = __shfl_xor(sv, j);
      int   oi = __shfl_xor(si, j);
      bool up = ((lane & k) == 0);
      bool lower = ((lane & j) == 0);
      bool osm = (ov < sv) || (ov == sv && oi < si);
      bool take = (lower == up) ? osm : !osm;
      if (take) { sv = ov; si = oi; }
    }
  }
}

// ---------------- prep: fc1 MFMA + weight pre-pack + p4 pack (no stats) ----------------
__global__ __launch_bounds__(256) void prep_kernel(
    const float* __restrict__ x, const float* __restrict__ w,
    const float* __restrict__ bias,
    const float* __restrict__ aw1, const float* __restrict__ aw2,
    const float* __restrict__ pw2, const float* __restrict__ qw,
    const float* __restrict__ f2w, const float* __restrict__ p,
    unsigned short* __restrict__ wpak, float* __restrict__ out,
    float4* __restrict__ p4) {
  __shared__ unsigned short wf[8 * 512];   // fc1_w B-frags, 8 KB
  const int t = threadIdx.x;
  const int blk = blockIdx.x;              // 256 blocks
  {
    int id = blk * 256 + t;
    if (id < 16384) {
      int j = id & 7, lane = (id >> 3) & 63, rest = id >> 9;
      int mt = rest >> 1, hh = rest & 1;
      wpak[id] = f2bf(aw1[(32 * hh + 8 * (lane >> 4) + j) * 256 + mt * 16 + (lane & 15)]);
    } else if (id < 32768) {
      int i = id - 16384;
      int j = i & 7, lane = (i >> 3) & 63, rest = i >> 9;
      int ct = rest >> 3, f = rest & 7;
      wpak[id] = f2bf(aw2[(32 * f + 8 * (lane >> 4) + j) * 64 + ct * 16 + (lane & 15)]);
    } else if (id < 34816) {
      int i = id - 32768;
      int c = i >> 5, hh = i & 31;
      wpak[id] = f2bf(pw2[hh * 64 + c]);
    } else if (id < 47104) {
      int i = id - 34816;
      int j = i & 7, lane = (i >> 3) & 63, rest = i >> 9;
      int ct = rest >> 1, hh = rest & 1;
      wpak[id] = f2bf(qw[(32 * hh + 8 * (lane >> 4) + j) * 192 + ct * 16 + (lane & 15)]);
    } else if (id < 51200) {
      int i = id - 47104;
      int j = i & 7, lane = (i >> 3) & 63, rest = i >> 9;
      int ct = rest >> 1, hh = rest & 1;
      wpak[id] = f2bf(f2w[(32 * hh + 8 * (lane >> 4) + j) * 64 + ct * 16 + (lane & 15)]);
    }
  }
  // p4 pack: 64 points per block
  if (t < 64) {
    int idx = blk * 64 + t;
    float px = p[3 * idx], py = p[3 * idx + 1], pz = p[3 * idx + 2];
    p4[idx] = make_float4(px, py, pz, px * px + py * py + pz * pz);
  }
  for (int i = t; i < 4096; i += 256) {
    int j = i & 7, lane = (i >> 3) & 63, rest = i >> 9;
    int ct = rest >> 1, hh = rest & 1;
    wf[i] = f2bf(w[(32 * hh + 8 * (lane >> 4) + j) * 64 + ct * 16 + (lane & 15)]);
  }
  __syncthreads();
  const int lane = t & 63, wv = t >> 6;
  const int l = lane & 15, q = lane >> 4;
  const int r0 = blk * 64;
  const int row = r0 + wv * 16 + l;
  const f32x4 zero = {0.f, 0.f, 0.f, 0.f};
  float4 xa0 = *reinterpret_cast<const float4*>(&x[row * 64 + q * 8]);
  float4 xa1 = *reinterpret_cast<const float4*>(&x[row * 64 + q * 8 + 4]);
  float4 xb0 = *reinterpret_cast<const float4*>(&x[row * 64 + 32 + q * 8]);
  float4 xb1 = *reinterpret_cast<const float4*>(&x[row * 64 + 32 + q * 8 + 4]);
  short8 a0 = pack8f(xa0, xa1), a1 = pack8f(xb0, xb1);
  #pragma unroll
  for (int ct = 0; ct < 4; ++ct) {
    short8 b0 = *reinterpret_cast<const short8*>(&wf[(ct * 2 + 0) * 512 + lane * 8]);
    short8 b1v = *reinterpret_cast<const short8*>(&wf[(ct * 2 + 1) * 512 + lane * 8]);
    f32x4 acc = __builtin_amdgcn_mfma_f32_16x16x32_bf16(a0, b0, zero, 0, 0, 0);
    acc = __builtin_amdgcn_mfma_f32_16x16x32_bf16(a1, b1v, acc, 0, 0, 0);
    const float bc = bias[ct * 16 + l];
    #pragma unroll
    for (int i = 0; i < 4; ++i)
      out[(r0 + wv * 16 + q * 4 + i) * 64 + ct * 16 + l] = acc[i] + bc;
  }
}

// ---------------- batchnorm stats (R9-proven, no atomics) ----------------
__global__ void stats_part_kernel(const float* __restrict__ src, float* __restrict__ part) {
  __shared__ float sb[256], sb2[256];
  const int t = threadIdx.x, blk = blockIdx.x;
  const int c = t & 63, rg = t >> 6;
  float s = 0.f, s2 = 0.f;
  for (int r = rg; r < 64; r += 4) {
    float v = src[(blk * 64 + r) * 64 + c];
    s += v; s2 += v * v;
  }
  sb[t] = s; sb2[t] = s2; __syncthreads();
  if (t < 64) {
    float ts  = sb[t] + sb[64 + t] + sb[128 + t] + sb[192 + t];
    float ts2 = sb2[t] + sb2[64 + t] + sb2[128 + t] + sb2[192 + t];
    part[blk * 128 + t] = ts;
    part[blk * 128 + 64 + t] = ts2;
  }
}

// emits affine form: A = g*rs, B = b - mu*g*rs  (bn(v) = A*v + B)
__global__ void stats_fin_kernel(const float* __restrict__ part,
                                 const float* __restrict__ g, const float* __restrict__ b,
                                 float* __restrict__ A, float* __restrict__ Bv) {
  const int c = threadIdx.x;  // 64
  double s = 0.0, s2 = 0.0;
  for (int i = 0; i < 256; ++i) { s += part[i * 128 + c]; s2 += part[i * 128 + 64 + c]; }
  double mean = s / (double)kRows;
  double var = s2 / (double)kRows - mean * mean;
  float rs = (float)(1.0 / sqrt(var + (double)kEps));
  float Af = g[c] * rs;
  A[c] = Af;
  Bv[c] = b[c] - (float)mean * Af;
}

// ---------------- fused qkv (blocks 0..255) + knn (blocks 256..4351), R10-proven ----------------
__global__ __launch_bounds__(256) void qkv_knn_kernel(
    const float* __restrict__ hpre, const float* __restrict__ A1,
    const float* __restrict__ B1, const unsigned short* __restrict__ wqf,
    float* __restrict__ hout, unsigned short* __restrict__ qkvout,
    const float4* __restrict__ p4, int* __restrict__ idxf) {
  __shared__ float bufv[4][kCap];
  __shared__ int   bufi[4][kCap];
  __shared__ int   cnt[4];
  const int t = threadIdx.x;
  const int lane = t & 63, w = t >> 6;

  if (blockIdx.x < 256) {
    const int l = lane & 15, q = lane >> 4;
    const int r0 = blockIdx.x * 64;
    const int row = r0 + w * 16 + l;
    const f32x4 zero = {0.f, 0.f, 0.f, 0.f};
    short8 af[2];
    #pragma unroll
    for (int hh = 0; hh < 2; ++hh) {
      const int c0 = 32 * hh + q * 8;
      float4 v0 = *reinterpret_cast<const float4*>(&hpre[row * 64 + c0]);
      float4 v1 = *reinterpret_cast<const float4*>(&hpre[row * 64 + c0 + 4]);
      float4 Aa = *reinterpret_cast<const float4*>(&A1[c0]);
      float4 Ab = *reinterpret_cast<const float4*>(&A1[c0 + 4]);
      float4 Ba = *reinterpret_cast<const float4*>(&B1[c0]);
      float4 Bb = *reinterpret_cast<const float4*>(&B1[c0 + 4]);
      v0.x = fmaxf(Aa.x * v0.x + Ba.x, 0.f); v0.y = fmaxf(Aa.y * v0.y + Ba.y, 0.f);
      v0.z = fmaxf(Aa.z * v0.z + Ba.z, 0.f); v0.w = fmaxf(Aa.w * v0.w + Ba.w, 0.f);
      v1.x = fmaxf(Ab.x * v1.x + Bb.x, 0.f); v1.y = fmaxf(Ab.y * v1.y + Bb.y, 0.f);
      v1.z = fmaxf(Ab.z * v1.z + Bb.z, 0.f); v1.w = fmaxf(Ab.w * v1.w + Bb.w, 0.f);
      *reinterpret_cast<float4*>(&hout[row * 64 + c0]) = v0;
      *reinterpret_cast<float4*>(&hout[row * 64 + c0 + 4]) = v1;
      af[hh] = pack8f(v0, v1);
    }
    #pragma unroll
    for (int ct = 0; ct < 12; ++ct) {
      short8 b0 = *reinterpret_cast<const short8*>(&wqf[((ct * 2 + 0) * 64 + lane) * 8]);
      short8 b1 = *reinterpret_cast<const short8*>(&wqf[((ct * 2 + 1) * 64 + lane) * 8]);
      f32x4 acc = __builtin_amdgcn_mfma_f32_16x16x32_bf16(af[0], b0, zero, 0, 0, 0);
      acc = __builtin_amdgcn_mfma_f32_16x16x32_bf16(af[1], b1, acc, 0, 0, 0);
      #pragma unroll
      for (int i = 0; i < 4; ++i)
        qkvout[(r0 + w * 16 + q * 4 + i) * 192 + ct * 16 + l] = f2bf(acc[i]);
    }
    return;
  }

  // ---- knn branch: barrier-free filtered top-16 over packed p4 ----
  const int blk = blockIdx.x - 256;
  const int b = blk >> 10;
  const int q = blk * 4 + w;
  const float4 qp = p4[q];
  const float m2x = -2.0f * qp.x, m2y = -2.0f * qp.y, m2z = -2.0f * qp.z;
  const float sqw = qp.w;
  if (lane == 0) cnt[w] = 0;
  const int base = b * kN;

  float d2r[16];
  float lmin = kFltMax;
  #pragma unroll
  for (int i = 0; i < 16; ++i) {
    float4 c = p4[base + i * 64 + lane];
    float d2 = fmaf(m2x, c.x, fmaf(m2y, c.y, fmaf(m2z, c.z, sqw + c.w)));
    d2r[i] = d2;
    lmin = fminf(lmin, d2);
  }
  { int dummy = lane; bitonic64(lmin, dummy, lane); }
  const float thrA = __shfl(lmin, 15) + 1e-3f;  // cross-site FMA-wobble margin

  #pragma unroll
  for (int i = 0; i < 16; ++i) {
    if (d2r[i] <= thrA) {
      int pos = atomicAdd(&cnt[w], 1);
      if (pos < kCap) { bufv[w][pos] = d2r[i]; bufi[w][pos] = i * 64 + lane; }
    }
  }
  for (int i = 16; i < 64; ++i) {
    float4 c = p4[base + i * 64 + lane];
    float d2 = fmaf(m2x, c.x, fmaf(m2y, c.y, fmaf(m2z, c.z, sqw + c.w)));
    if (d2 <= thrA) {
      int pos = atomicAdd(&cnt[w], 1);
      if (pos < kCap) { bufv[w][pos] = d2; bufi[w][pos] = i * 64 + lane; }
    }
  }

  const int n = cnt[w];
  float sv = kFltMax;
  int   si = 0x7fffffff;
  if (n <= kCap) {
    for (int g0 = 0; g0 < n; g0 += 48) {
      float mv; int mi;
      if (lane < 16) { mv = sv; mi = si; }
      else {
        int pos = g0 + (lane - 16);
        if (pos < n) { mv = bufv[w][pos]; mi = bufi[w][pos]; }
        else { mv = kFltMax; mi = 0x7fffffff; }
      }
      bitonic64(mv, mi, lane);
      sv = mv; si = mi;
    }
  } else {
    for (int g0 = 0; g0 < kN; g0 += 48) {   // degenerate-data slow path
      float mv; int mi;
      if (lane < 16) { mv = sv; mi = si; }
      else {
        int j = g0 + (lane - 16);
        if (j < kN) {
          float4 c = p4[base + j];
          mv = fmaf(m2x, c.x, fmaf(m2y, c.y, fmaf(m2z, c.z, sqw + c.w)));
          mi = j;
        } else { mv = kFltMax; mi = 0x7fffffff; }
      }
      bitonic64(mv, mi, lane);
      sv = mv; si = mi;
    }
  }
  if (lane < 16) {
    int out = si;
    if ((unsigned)out >= (unsigned)kN) out = 0;  // safety net: wrong beats fault
    idxf[q * 16 + lane] = out;
  }
}

// ---------------- fused MFMA attention v4 (byte-identical to R9's 75.8 us version) ----------------
__global__ __launch_bounds__(256) void attn_mfma4_kernel(
    const float* __restrict__ p, const unsigned short* __restrict__ qkv,
    const int* __restrict__ idxf,
    const float* __restrict__ pos_w1, const float* __restrict__ pos_b1,
    const float* __restrict__ pos_b2,
    const float* __restrict__ attn_b1, const float* __restrict__ attn_b2,
    const unsigned short* __restrict__ w1f,
    const unsigned short* __restrict__ w2f,
    const unsigned short* __restrict__ pw2t,
    float* __restrict__ agg) {
  __shared__ unsigned short Ulds[64 * 72];   // [row][c] bf16, stride 72
  __shared__ float VVlds[64 * 68];           // [row][c] fp32, stride 68

  const int t = threadIdx.x;
  const int lane = t & 63, w = t >> 6;
  const int l = lane & 15, q = lane >> 4;
  const int work = ((blockIdx.x & 7) << 9) | (blockIdx.x >> 3);  // XCD swizzle
  const int b = work >> 10;
  const int n0 = (work & 1023) * 4;
  const int pt_row = b * kN + n0 + w;
  const f32x4 zero = {0.f, 0.f, 0.f, 0.f};

  int idxv = 0;
  if (lane < 16) idxv = idxf[(work * 4 + w) * 16 + lane];

  // phase 1a: gather k/v (bf16); U = bf16(q - k); VV[row][c] = v
  {
    const int r = lane >> 2, seg = lane & 3;
    const unsigned short* jrow = qkv + (b * kN + __shfl(idxv, r)) * 192;
    const int c0 = seg * 16;
    uint4 k0 = *reinterpret_cast<const uint4*>(jrow + 64 + c0);
    uint4 k1 = *reinterpret_cast<const uint4*>(jrow + 64 + c0 + 8);
    uint4 v0 = *reinterpret_cast<const uint4*>(jrow + 128 + c0);
    uint4 v1 = *reinterpret_cast<const uint4*>(jrow + 128 + c0 + 8);
    uint4 q0 = *reinterpret_cast<const uint4*>(qkv + pt_row * 192 + c0);
    uint4 q1 = *reinterpret_cast<const uint4*>(qkv + pt_row * 192 + c0 + 8);
    auto diff2 = [](unsigned int qu, unsigned int ku) -> unsigned int {
      float lo = __uint_as_float(qu << 16) - __uint_as_float(ku << 16);
      float hi = __uint_as_float(qu & 0xffff0000u) - __uint_as_float(ku & 0xffff0000u);
      return pkbf(lo, hi);
    };
    uint4 u0, u1;
    u0.x = diff2(q0.x, k0.x); u0.y = diff2(q0.y, k0.y);
    u0.z = diff2(q0.z, k0.z); u0.w = diff2(q0.w, k0.w);
    u1.x = diff2(q1.x, k1.x); u1.y = diff2(q1.y, k1.y);
    u1.z = diff2(q1.z, k1.z); u1.w = diff2(q1.w, k1.w);
    *reinterpret_cast<uint4*>(&Ulds[(w * 16 + r) * 72 + c0]) = u0;
    *reinterpret_cast<uint4*>(&Ulds[(w * 16 + r) * 72 + c0 + 8]) = u1;
    const unsigned int vs[8] = {v0.x, v0.y, v0.z, v0.w, v1.x, v1.y, v1.z, v1.w};
    #pragma unroll
    for (int i = 0; i < 4; ++i) {
      float4 vv;
      vv.x = __uint_as_float(vs[2 * i] << 16);
      vv.y = __uint_as_float(vs[2 * i] & 0xffff0000u);
      vv.z = __uint_as_float(vs[2 * i + 1] << 16);
      vv.w = __uint_as_float(vs[2 * i + 1] & 0xffff0000u);
      *reinterpret_cast<float4*>(&VVlds[(w * 16 + r) * 68 + c0 + 4 * i]) = vv;
    }
  }
  // phase 1b: pe hidden (3->32) — registers only
  short8 pbf;
  {
    const float3 pn = *reinterpret_cast<const float3*>(p + pt_row * 3);
    const int nj = __shfl(idxv, l);
    const float3 pj = *reinterpret_cast<const float3*>(p + (b * kN + nj) * 3);
    float rx = pn.x - pj.x, ry = pn.y - pj.y, rz = pn.z - pj.z;
    float hv[8];
    #pragma unroll
    for (int j = 0; j < 8; ++j) {
      int hh = q * 8 + j;
      hv[j] = fmaxf(pos_b1[hh] + rx * pos_w1[hh] + ry * pos_w1[32 + hh] +
                    rz * pos_w1[64 + hh], 0.0f);
    }
    union { unsigned int u[4]; short8 s; } pk;
    #pragma unroll
    for (int ii = 0; ii < 4; ++ii) pk.u[ii] = pkbf(hv[2 * ii], hv[2 * ii + 1]);
    pbf = pk.s;
  }

  // phase 2: pe = pehid @ pos_w2 (transposed MFMA, D[c][row]); RMW U and VV
  {
    const int urow = (w * 16 + l) * 72;
    const int vrow = (w * 16 + l) * 68;
    #pragma unroll
    for (int mt = 0; mt < 4; ++mt) {
      short8 paf = *reinterpret_cast<const short8*>(&pw2t[(mt * 16 + l) * 32 + q * 8]);
      f32x4 pe = __builtin_amdgcn_mfma_f32_16x16x32_bf16(paf, pbf, zero, 0, 0, 0);
      const int c0 = mt * 16 + q * 4;
      float4 b2v = *reinterpret_cast<const float4*>(&pos_b2[c0]);
      float pe0 = pe[0] + b2v.x, pe1 = pe[1] + b2v.y;
      float pe2 = pe[2] + b2v.z, pe3 = pe[3] + b2v.w;
      uint2 u2 = *reinterpret_cast<uint2*>(&Ulds[urow + c0]);
      uint2 o;
      o.x = pkbf(__uint_as_float(u2.x << 16) + pe0,
                 __uint_as_float(u2.x & 0xffff0000u) + pe1);
      o.y = pkbf(__uint_as_float(u2.y << 16) + pe2,
                 __uint_as_float(u2.y & 0xffff0000u) + pe3);
      *reinterpret_cast<uint2*>(&Ulds[urow + c0]) = o;
      float4 vv = *reinterpret_cast<float4*>(&VVlds[vrow + c0]);
      vv.x += pe0; vv.y += pe1; vv.z += pe2; vv.w += pe3;
      *reinterpret_cast<float4*>(&VVlds[vrow + c0]) = vv;
    }
  }

  // phase 3: GEMM1 transposed; H packed to bf16 dwords immediately
  unsigned int plo[16], phi[16];
  {
    const int urow = (w * 16 + l) * 72;
    short8 ub0 = *reinterpret_cast<const short8*>(&Ulds[urow + q * 8]);
    short8 ub1 = *reinterpret_cast<const short8*>(&Ulds[urow + 32 + q * 8]);
    #pragma unroll
    for (int mt = 0; mt < 16; ++mt) {
      short8 a0 = *reinterpret_cast<const short8*>(&w1f[(mt * 2 + 0) * 512 + lane * 8]);
      short8 a1 = *reinterpret_cast<const short8*>(&w1f[(mt * 2 + 1) * 512 + lane * 8]);
      f32x4 acc = __builtin_amdgcn_mfma_f32_16x16x32_bf16(a0, ub0, zero, 0, 0, 0);
      acc = __builtin_amdgcn_mfma_f32_16x16x32_bf16(a1, ub1, acc, 0, 0, 0);
      float4 bb = *reinterpret_cast<const float4*>(&attn_b1[mt * 16 + q * 4]);
      plo[mt] = pkbf(fmaxf(acc[0] + bb.x, 0.f), fmaxf(acc[1] + bb.y, 0.f));
      phi[mt] = pkbf(fmaxf(acc[2] + bb.z, 0.f), fmaxf(acc[3] + bb.w, 0.f));
    }
  }

  // phase 4: GEMM2 via cheap repack; softmax; weighted sum of VV
  {
    f32x4 acc2[4];
    #pragma unroll
    for (int ct = 0; ct < 4; ++ct) acc2[ct] = zero;
    const int sbase = l + 32 * (q & 1);
    const bool hi_mt = (q >= 2);
    #pragma unroll
    for (int f = 0; f < 8; ++f) {
      union { unsigned int u[4]; short8 s; } pk;
      #pragma unroll
      for (int d = 0; d < 4; ++d) {
        const int src = sbase + ((d >> 1) << 4);
        const unsigned int w0 = (d & 1) ? phi[2 * f] : plo[2 * f];
        const unsigned int w1v = (d & 1) ? phi[2 * f + 1] : plo[2 * f + 1];
        unsigned int va = (unsigned int)__shfl((int)w0, src);
        unsigned int vb = (unsigned int)__shfl((int)w1v, src);
        pk.u[d] = hi_mt ? vb : va;
      }
      short8 afr = pk.s;
      #pragma unroll
      for (int ct = 0; ct < 4; ++ct) {
        short8 bfr = *reinterpret_cast<const short8*>(&w2f[((ct * 8 + f) * 64 + lane) * 8]);
        acc2[ct] = __builtin_amdgcn_mfma_f32_16x16x32_bf16(afr, bfr, acc2[ct], 0, 0, 0);
      }
    }
    #pragma unroll
    for (int ct = 0; ct < 4; ++ct) {
      const int ch = ct * 16 + l;
      const float bv = attn_b2[ch];
      float s0v = acc2[ct][0] + bv, s1v = acc2[ct][1] + bv;
      float s2v = acc2[ct][2] + bv, s3v = acc2[ct][3] + bv;
      float mx = fmaxf(fmaxf(s0v, s1v), fmaxf(s2v, s3v));
      mx = fmaxf(mx, __shfl_xor(mx, 16, 64));
      mx = fmaxf(mx, __shfl_xor(mx, 32, 64));
      float e0 = __expf(s0v - mx), e1 = __expf(s1v - mx);
      float e2 = __expf(s2v - mx), e3 = __expf(s3v - mx);
      float se = e0 + e1 + e2 + e3;
      se += __shfl_xor(se, 16, 64);
      se += __shfl_xor(se, 32, 64);
      const int vbase = (w * 16 + q * 4) * 68 + ch;
      float a = e0 * VVlds[vbase] + e1 * VVlds[vbase + 68] +
                e2 * VVlds[vbase + 136] + e3 * VVlds[vbase + 204];
      a += __shfl_xor(a, 16, 64);
      a += __shfl_xor(a, 32, 64);
      if (q == 0) agg[(work * 4 + w) * 64 + ch] = a / se;
    }
  }
}

// ---------------- fc2 (MFMA) with fused bn2+relu+residual prologue (R9-proven) ----------------
__global__ __launch_bounds__(256) void fc2_mfma_kernel(
    const float* __restrict__ aggp, const float* __restrict__ hres,
    const float* __restrict__ A2, const float* __restrict__ B2,
    const unsigned short* __restrict__ fc2f, const float* __restrict__ bias,
    float* __restrict__ z) {
  const int t = threadIdx.x, lane = t & 63, wv = t >> 6;
  const int l = lane & 15, q = lane >> 4;
  const int r0 = blockIdx.x * 64;
  const int row = r0 + wv * 16 + l;
  const f32x4 zero = {0.f, 0.f, 0.f, 0.f};
  short8 af[2];
  #pragma unroll
  for (int hh = 0; hh < 2; ++hh) {
    const int c0 = 32 * hh + q * 8;
    float4 v0 = *reinterpret_cast<const float4*>(&aggp[row * 64 + c0]);
    float4 v1 = *reinterpret_cast<const float4*>(&aggp[row * 64 + c0 + 4]);
    float4 r0v = *reinterpret_cast<const float4*>(&hres[row * 64 + c0]);
    float4 r1v = *reinterpret_cast<const float4*>(&hres[row * 64 + c0 + 4]);
    float4 Aa = *reinterpret_cast<const float4*>(&A2[c0]);
    float4 Ab = *reinterpret_cast<const float4*>(&A2[c0 + 4]);
    float4 Ba = *reinterpret_cast<const float4*>(&B2[c0]);
    float4 Bb = *reinterpret_cast<const float4*>(&B2[c0 + 4]);
    v0.x = fmaxf(Aa.x * v0.x + Ba.x, 0.f) + r0v.x;
    v0.y = fmaxf(Aa.y * v0.y + Ba.y, 0.f) + r0v.y;
    v0.z = fmaxf(Aa.z * v0.z + Ba.z, 0.f) + r0v.z;
    v0.w = fmaxf(Aa.w * v0.w + Ba.w, 0.f) + r0v.w;
    v1.x = fmaxf(Ab.x * v1.x + Bb.x, 0.f) + r1v.x;
    v1.y = fmaxf(Ab.y * v1.y + Bb.y, 0.f) + r1v.y;
    v1.z = fmaxf(Ab.z * v1.z + Bb.z, 0.f) + r1v.z;
    v1.w = fmaxf(Ab.w * v1.w + Bb.w, 0.f) + r1v.w;
    af[hh] = pack8f(v0, v1);
  }
  #pragma unroll
  for (int ct = 0; ct < 4; ++ct) {
    short8 b0 = *reinterpret_cast<const short8*>(&fc2f[((ct * 2 + 0) * 64 + lane) * 8]);
    short8 b1 = *reinterpret_cast<const short8*>(&fc2f[((ct * 2 + 1) * 64 + lane) * 8]);
    f32x4 acc = __builtin_amdgcn_mfma_f32_16x16x32_bf16(af[0], b0, zero, 0, 0, 0);
    acc = __builtin_amdgcn_mfma_f32_16x16x32_bf16(af[1], b1, acc, 0, 0, 0);
    const float bc = bias[ct * 16 + l];
    #pragma unroll
    for (int i = 0; i < 4; ++i)
      z[(r0 + wv * 16 + q * 4 + i) * 64 + ct * 16 + l] = acc[i] + bc;
  }
}

// ---------------- final bn3+relu, fused p-copy ----------------
__global__ void final_kernel(const float* __restrict__ z, const float* __restrict__ A3,
                             const float* __restrict__ B3, const float* __restrict__ p,
                             float* __restrict__ y) {
  const int blk = blockIdx.x, t = threadIdx.x;
  if (blk < 4096) {
    int i = blk * 256 + t;
    int c = i & 63;
    y[i] = fmaxf(A3[c] * z[i] + B3[c], 0.0f);
  } else {
    int i = (blk - 4096) * 256 + t;
    y[1048576 + i] = p[i];
  }
}

extern "C" void kernel_launch(void* const* d_in, const int* in_sizes, int n_in,
                              void* d_out, int out_size, void* d_ws, size_t ws_size,
                              hipStream_t stream) {
  const float* x       = (const float*)d_in[0];
  const float* p       = (const float*)d_in[1];
  const float* fc1_w   = (const float*)d_in[2];
  const float* fc1_b   = (const float*)d_in[3];
  const float* bn1_g   = (const float*)d_in[4];
  const float* bn1_b   = (const float*)d_in[5];
  const float* qkv_w   = (const float*)d_in[6];
  const float* pos_w1  = (const float*)d_in[7];
  const float* pos_b1  = (const float*)d_in[8];
  const float* pos_w2  = (const float*)d_in[9];
  const float* pos_b2  = (const float*)d_in[10];
  const float* attn_w1 = (const float*)d_in[11];
  const float* attn_b1 = (const float*)d_in[12];
  const float* attn_w2 = (const float*)d_in[13];
  const float* attn_b2 = (const float*)d_in[14];
  const float* bn2_g   = (const float*)d_in[15];
  const float* bn2_b   = (const float*)d_in[16];
  const float* fc2_w   = (const float*)d_in[17];
  const float* fc2_b   = (const float*)d_in[18];
  const float* bn3_g   = (const float*)d_in[19];
  const float* bn3_b   = (const float*)d_in[20];

  float* ws   = (float*)d_ws;
  float* h    = ws;                     // residual, fp32
  unsigned short* qkvb = (unsigned short*)(ws + 1048576);  // bf16 [16384][192]
  float* hpre = ws + 4194304;
  float* aggv = ws + 5242880;           // also stats partials 1,3
  float* z    = ws + 6291456;           // also stats partials 2 (after p4 dead)
  float4* p4  = (float4*)(ws + 6291456);   // aliases z: consumed (knn) before reuse
  float* st   = ws + 7340032;              // A1,B1,A2,B2,A3,B3 (384 floats)
  int*   idxf  = (int*)(ws + 7356800);
  unsigned short* wpak = (unsigned short*)(ws + 7618944);
  unsigned short* w1f  = wpak;
  unsigned short* w2f  = wpak + 16384;
  unsigned short* pw2t = wpak + 32768;
  unsigned short* wqf  = wpak + 34816;
  unsigned short* fc2f = wpak + 47104;

  float* A1 = st,       *B1 = st + 64;
  float* A2 = st + 128, *B2 = st + 192;
  float* A3 = st + 256, *B3 = st + 320;
  float* y = (float*)d_out;

  prep_kernel<<<256, 256, 0, stream>>>(x, fc1_w, fc1_b, attn_w1, attn_w2, pos_w2,
                                       qkv_w, fc2_w, p, wpak, hpre, p4);
  stats_part_kernel<<<256, 256, 0, stream>>>(hpre, aggv);
  stats_fin_kernel<<<1, 64, 0, stream>>>(aggv, bn1_g, bn1_b, A1, B1);
  qkv_knn_kernel<<<4352, 256, 0, stream>>>(hpre, A1, B1, wqf, h, qkvb, p4, idxf);
  attn_mfma4_kernel<<<4096, 256, 0, stream>>>(p, qkvb, idxf, pos_w1, pos_b1, pos_b2,
                                              attn_b1, attn_b2, w1f, w2f, pw2t, aggv);
  stats_part_kernel<<<256, 256, 0, stream>>>(aggv, z);
  stats_fin_kernel<<<1, 64, 0, stream>>>(z, bn2_g, bn2_b, A2, B2);
  fc2_mfma_kernel<<<256, 256, 0, stream>>>(aggv, h, A2, B2, fc2f, fc2_b, z);
  stats_part_kernel<<<256, 256, 0, stream>>>(z, aggv);
  stats_fin_kernel<<<1, 64, 0, stream>>>(aggv, bn3_g, bn3_b, A3, B3);
  final_kernel<<<4288, 256, 0, stream>>>(z, A3, B3, p, y);
}